// Round 2
// baseline (194.705 us; speedup 1.0000x reference)
//
#include <hip/hip_runtime.h>

#define KK 40        // N_RADIAL * N_ANGULAR
#define M3 120       // KK * 3
#define FEAT 16
#define NT 8
#define ODIM 32
#define VPB 128      // vertices per block
#define BLOCK 256

typedef unsigned int u32;
typedef unsigned short u16;

// cs3[m] = csum[m/3], csum[k] = sum_{ra} ic[ra][k]
__global__ void cs3_kernel(const float* __restrict__ ic, float* __restrict__ cs3) {
    __shared__ float cs[KK];
    const int t = threadIdx.x;
    if (t < KK) {
        float s = 0.f;
        #pragma unroll
        for (int ra = 0; ra < KK; ++ra) s += ic[ra * KK + t];
        cs[t] = s;
    }
    __syncthreads();
    if (t < M3) cs3[t] = cs[t / 3];
}

__device__ __forceinline__ u16 f2bf_rne(float x) {
    u32 u = __float_as_uint(x);
    u32 r = (u + 0x7fffu + ((u >> 16) & 1u)) >> 16;   // round-to-nearest-even
    return (u16)r;
}

// mesh fp32 -> bf16, 8 elements per thread
__global__ void cvt_kernel(const float* __restrict__ mesh, u16* __restrict__ mbf, int total) {
    const int i = blockIdx.x * blockDim.x + threadIdx.x;
    const int base = i * 8;
    if (base < total) {
        float4 a = *(const float4*)(mesh + base);
        float4 b = *(const float4*)(mesh + base + 4);
        u32 p0 = (u32)f2bf_rne(a.x) | ((u32)f2bf_rne(a.y) << 16);
        u32 p1 = (u32)f2bf_rne(a.z) | ((u32)f2bf_rne(a.w) << 16);
        u32 p2 = (u32)f2bf_rne(b.x) | ((u32)f2bf_rne(b.y) << 16);
        u32 p3 = (u32)f2bf_rne(b.z) | ((u32)f2bf_rne(b.w) << 16);
        uint4 v = make_uint4(p0, p1, p2, p3);
        *(uint4*)(mbf + base) = v;
    }
}

template<bool USE_BF16>
__global__ __launch_bounds__(BLOCK, 8) void conv_kernel(
    const float* __restrict__ mesh,   // [N,16] fp32
    const u16*   __restrict__ mbf,    // [N,16] bf16 (valid iff USE_BF16)
    const float* __restrict__ bw,     // [N,120]
    const float* __restrict__ W,      // [8,32,16]
    const float* __restrict__ bias,   // [8,32]
    const int*   __restrict__ bi,     // [N,120]
    const float* __restrict__ cs3,    // [120]
    float*       __restrict__ out,    // [N,32]
    int n)
{
    __shared__ float s_sig[VPB][FEAT + 1];   // stride 17 dwords -> <=2-way banks
    __shared__ float s_cs3[M3];

    const int tid = threadIdx.x;
    if (tid < M3) s_cs3[tid] = cs3[tid];
    __syncthreads();

    // ---------------- Phase 1: gather + interp ----------------
    // 2 lanes per vertex; lane q handles 8 features (one 16B bf16 chunk).
    {
        const int vloc = tid >> 1;
        const int q    = tid & 1;
        const int vg   = blockIdx.x * VPB + vloc;

        float acc[8];
        #pragma unroll
        for (int e = 0; e < 8; ++e) acc[e] = 0.f;

        if (vg < n) {
            const float4* bw4 = (const float4*)(bw + (size_t)vg * M3);
            const int4*   bi4 = (const int4*)(bi + (size_t)vg * M3);
            #pragma unroll 3
            for (int mm = 0; mm < 30; ++mm) {
                const float4 wv = bw4[mm];
                const int4   iv = bi4[mm];
                const int mb = mm * 4;
                float ws[4];
                ws[0] = s_cs3[mb + 0] * wv.x;
                ws[1] = s_cs3[mb + 1] * wv.y;
                ws[2] = s_cs3[mb + 2] * wv.z;
                ws[3] = s_cs3[mb + 3] * wv.w;
                int idxs[4] = {iv.x, iv.y, iv.z, iv.w};
                #pragma unroll
                for (int j = 0; j < 4; ++j) {
                    const float w = ws[j];
                    if (USE_BF16) {
                        const uint4 g = *((const uint4*)(mbf + (size_t)idxs[j] * FEAT) + q);
                        acc[0] = fmaf(w, __uint_as_float(g.x << 16),          acc[0]);
                        acc[1] = fmaf(w, __uint_as_float(g.x & 0xffff0000u), acc[1]);
                        acc[2] = fmaf(w, __uint_as_float(g.y << 16),          acc[2]);
                        acc[3] = fmaf(w, __uint_as_float(g.y & 0xffff0000u), acc[3]);
                        acc[4] = fmaf(w, __uint_as_float(g.z << 16),          acc[4]);
                        acc[5] = fmaf(w, __uint_as_float(g.z & 0xffff0000u), acc[5]);
                        acc[6] = fmaf(w, __uint_as_float(g.w << 16),          acc[6]);
                        acc[7] = fmaf(w, __uint_as_float(g.w & 0xffff0000u), acc[7]);
                    } else {
                        const float4* row = (const float4*)(mesh + (size_t)idxs[j] * FEAT) + q * 2;
                        const float4 r0 = row[0];
                        const float4 r1 = row[1];
                        acc[0] = fmaf(w, r0.x, acc[0]);
                        acc[1] = fmaf(w, r0.y, acc[1]);
                        acc[2] = fmaf(w, r0.z, acc[2]);
                        acc[3] = fmaf(w, r0.w, acc[3]);
                        acc[4] = fmaf(w, r1.x, acc[4]);
                        acc[5] = fmaf(w, r1.y, acc[5]);
                        acc[6] = fmaf(w, r1.z, acc[6]);
                        acc[7] = fmaf(w, r1.w, acc[7]);
                    }
                }
            }
        }
        #pragma unroll
        for (int e = 0; e < 8; ++e) s_sig[vloc][q * 8 + e] = acc[e];
    }
    __syncthreads();

    // ---------------- Phase 2: fold (W @ s, relu, sum over t) ----------------
    // lane = vertex; waves {0,1} own outputs [0,16), waves {2,3} own [16,32).
    {
        const int vloc  = tid & (VPB - 1);
        const int half  = __builtin_amdgcn_readfirstlane(tid >> 7);  // wave-uniform
        const int obase = half * 16;
        const int vg    = blockIdx.x * VPB + vloc;

        float s[FEAT];
        #pragma unroll
        for (int f = 0; f < FEAT; ++f) s[f] = s_sig[vloc][f];

        float oacc[16];
        #pragma unroll
        for (int oi = 0; oi < 16; ++oi) oacc[oi] = 0.f;

        #pragma unroll 2
        for (int t = 0; t < NT; ++t) {
            #pragma unroll
            for (int oi = 0; oi < 16; ++oi) {
                const int o = obase + oi;
                float pre = bias[t * ODIM + o];                        // scalar load
                const float* wrow = W + ((size_t)t * ODIM + o) * FEAT; // scalar loads
                #pragma unroll
                for (int f = 0; f < FEAT; ++f)
                    pre = fmaf(wrow[f], s[f], pre);
                oacc[oi] += fmaxf(pre, 0.f);
            }
        }

        if (vg < n) {
            float* op = out + (size_t)vg * ODIM + obase;
            *(float4*)(op + 0)  = make_float4(oacc[0],  oacc[1],  oacc[2],  oacc[3]);
            *(float4*)(op + 4)  = make_float4(oacc[4],  oacc[5],  oacc[6],  oacc[7]);
            *(float4*)(op + 8)  = make_float4(oacc[8],  oacc[9],  oacc[10], oacc[11]);
            *(float4*)(op + 12) = make_float4(oacc[12], oacc[13], oacc[14], oacc[15]);
        }
    }
}

extern "C" void kernel_launch(void* const* d_in, const int* in_sizes, int n_in,
                              void* d_out, int out_size, void* d_ws, size_t ws_size,
                              hipStream_t stream) {
    const float* mesh = (const float*)d_in[0];
    const float* bw   = (const float*)d_in[1];
    const float* ic   = (const float*)d_in[2];
    const float* W    = (const float*)d_in[3];
    const float* bias = (const float*)d_in[4];
    const int*   bi   = (const int*)d_in[5];
    float* out = (float*)d_out;

    const int n = in_sizes[0] / FEAT;   // N_VERTS
    const int total = n * FEAT;

    // workspace layout: [0,512) cs3, [512, 512 + n*16*2) bf16 mesh
    float* cs3 = (float*)d_ws;
    u16*   mbf = (u16*)((char*)d_ws + 512);
    const size_t need = 512 + (size_t)total * sizeof(u16);
    const bool use_bf16 = (ws_size >= need);

    cs3_kernel<<<1, 128, 0, stream>>>(ic, cs3);

    const int blocks = (n + VPB - 1) / VPB;
    if (use_bf16) {
        const int cvt_threads = (total + 7) / 8;
        cvt_kernel<<<(cvt_threads + BLOCK - 1) / BLOCK, BLOCK, 0, stream>>>(mesh, mbf, total);
        conv_kernel<true><<<blocks, BLOCK, 0, stream>>>(mesh, mbf, bw, W, bias, bi, cs3, out, n);
    } else {
        conv_kernel<false><<<blocks, BLOCK, 0, stream>>>(mesh, mbf, bw, W, bias, bi, cs3, out, n);
    }
}

// Round 3
// 138.297 us; speedup vs baseline: 1.4079x; 1.4079x over previous
//
#include <hip/hip_runtime.h>

#define KK 40        // N_RADIAL * N_ANGULAR
#define M3 120       // KK * 3
#define MM4 30       // M3 / 4 (float4 chunks of bw/bi)
#define FEAT 16
#define NT 8
#define ODIM 32
#define VPB 64       // vertices per block
#define BLOCK 256

typedef unsigned int u32;
typedef unsigned short u16;
typedef float  f32x4 __attribute__((ext_vector_type(4)));
typedef int    i32x4 __attribute__((ext_vector_type(4)));
typedef u32    u32x4 __attribute__((ext_vector_type(4)));

// cs3[m] = csum[m/3], csum[k] = sum_{ra} ic[ra][k]
__global__ void cs3_kernel(const float* __restrict__ ic, float* __restrict__ cs3) {
    __shared__ float cs[KK];
    const int t = threadIdx.x;
    if (t < KK) {
        float s = 0.f;
        #pragma unroll
        for (int ra = 0; ra < KK; ++ra) s += ic[ra * KK + t];
        cs[t] = s;
    }
    __syncthreads();
    if (t < M3) cs3[t] = cs[t / 3];
}

__device__ __forceinline__ u16 f2bf_rne(float x) {
    u32 u = __float_as_uint(x);
    u32 r = (u + 0x7fffu + ((u >> 16) & 1u)) >> 16;   // round-to-nearest-even
    return (u16)r;
}

// mesh fp32 -> bf16, 8 elements per thread, non-temporal both ways
__global__ void cvt_kernel(const float* __restrict__ mesh, u16* __restrict__ mbf, int total) {
    const int i = blockIdx.x * blockDim.x + threadIdx.x;
    const int base = i * 8;
    if (base < total) {
        f32x4 a = __builtin_nontemporal_load((const f32x4*)(mesh + base));
        f32x4 b = __builtin_nontemporal_load((const f32x4*)(mesh + base + 4));
        u32x4 v;
        v.x = (u32)f2bf_rne(a.x) | ((u32)f2bf_rne(a.y) << 16);
        v.y = (u32)f2bf_rne(a.z) | ((u32)f2bf_rne(a.w) << 16);
        v.z = (u32)f2bf_rne(b.x) | ((u32)f2bf_rne(b.y) << 16);
        v.w = (u32)f2bf_rne(b.z) | ((u32)f2bf_rne(b.w) << 16);
        __builtin_nontemporal_store(v, (u32x4*)(mbf + base));
    }
}

__global__ __launch_bounds__(BLOCK, 4) void conv_kernel(
    const u16*   __restrict__ mbf,    // [N,16] bf16, L2-resident (3.2 MB)
    const float* __restrict__ bw,     // [N,120]
    const float* __restrict__ W,      // [8,32,16]
    const float* __restrict__ bias,   // [8,32]
    const int*   __restrict__ bi,     // [N,120]
    const float* __restrict__ cs3,    // [120]
    float*       __restrict__ out,    // [N,32]
    int n)
{
    __shared__ float s_sig[VPB][FEAT + 1];   // stride 17 dwords: conflict-free
    __shared__ f32x4 s_cs34[MM4];

    const int tid = threadIdx.x;
    if (tid < MM4) s_cs34[tid] = ((const f32x4*)cs3)[tid];
    __syncthreads();

    // ---------------- Phase 1: gather + interp ----------------
    // 4 lanes per vertex: tid = vloc*4 + mc*2 + q
    //   mc in {0,1}: m-chunk (mm = mc, mc+2, ..., mc+28)
    //   q  in {0,1}: feature half (8 bf16 = one 16B gather)
    {
        const int vloc = tid >> 2;
        const int mc   = (tid >> 1) & 1;
        const int q    = tid & 1;
        const int vg   = blockIdx.x * VPB + vloc;

        float acc[8];
        #pragma unroll
        for (int e = 0; e < 8; ++e) acc[e] = 0.f;

        if (vg < n) {
            const f32x4* bw4 = (const f32x4*)(bw + (size_t)vg * M3);
            const i32x4* bi4 = (const i32x4*)(bi + (size_t)vg * M3);
            #pragma unroll 3
            for (int i = 0; i < 15; ++i) {
                const int mm = mc + 2 * i;
                const f32x4 wv = __builtin_nontemporal_load(bw4 + mm);
                const i32x4 iv = __builtin_nontemporal_load(bi4 + mm);
                const f32x4 c4 = s_cs34[mm];
                const float ws[4] = { c4.x * wv.x, c4.y * wv.y, c4.z * wv.z, c4.w * wv.w };
                const int idxs[4] = { iv.x, iv.y, iv.z, iv.w };
                #pragma unroll
                for (int j = 0; j < 4; ++j) {
                    const float w = ws[j];
                    const u32x4 g = *((const u32x4*)(mbf + (size_t)idxs[j] * FEAT) + q);
                    acc[0] = fmaf(w, __uint_as_float(g.x << 16),          acc[0]);
                    acc[1] = fmaf(w, __uint_as_float(g.x & 0xffff0000u), acc[1]);
                    acc[2] = fmaf(w, __uint_as_float(g.y << 16),          acc[2]);
                    acc[3] = fmaf(w, __uint_as_float(g.y & 0xffff0000u), acc[3]);
                    acc[4] = fmaf(w, __uint_as_float(g.z << 16),          acc[4]);
                    acc[5] = fmaf(w, __uint_as_float(g.z & 0xffff0000u), acc[5]);
                    acc[6] = fmaf(w, __uint_as_float(g.w << 16),          acc[6]);
                    acc[7] = fmaf(w, __uint_as_float(g.w & 0xffff0000u), acc[7]);
                }
            }
        }

        // reduce across the two m-chunks (lanes differing in bit 1)
        #pragma unroll
        for (int e = 0; e < 8; ++e)
            acc[e] += __shfl_xor(acc[e], 2);

        // both mc lanes hold the full 8-feature sum; each writes its float4 quarter
        f32x4 v = (mc == 0) ? (f32x4){acc[0], acc[1], acc[2], acc[3]}
                            : (f32x4){acc[4], acc[5], acc[6], acc[7]};
        *(f32x4*)(&s_sig[vloc][q * 8 + mc * 4]) = v;
    }
    __syncthreads();

    // ---------------- Phase 2: fold (W @ s, relu, sum over t) ----------------
    // lane = vertex; wave w owns outputs o in [8w, 8w+8) for ALL templates.
    {
        const int lane = tid & 63;
        const int wave = __builtin_amdgcn_readfirstlane(tid >> 6);  // 0..3, SGPR
        const int vg2  = blockIdx.x * VPB + lane;

        float s[FEAT];
        #pragma unroll
        for (int f = 0; f < FEAT; ++f) s[f] = s_sig[lane][f];

        float oacc[8];
        #pragma unroll
        for (int oi = 0; oi < 8; ++oi) oacc[oi] = 0.f;

        #pragma unroll 2
        for (int t = 0; t < NT; ++t) {
            #pragma unroll
            for (int oi = 0; oi < 8; ++oi) {
                const int o = wave * 8 + oi;
                float pre = bias[t * ODIM + o];                        // scalar load
                const float* wrow = W + ((size_t)t * ODIM + o) * FEAT; // scalar loads
                #pragma unroll
                for (int f = 0; f < FEAT; ++f)
                    pre = fmaf(wrow[f], s[f], pre);
                oacc[oi] += fmaxf(pre, 0.f);
            }
        }

        if (vg2 < n) {
            float* op = out + (size_t)vg2 * ODIM + wave * 8;
            f32x4 v0 = {oacc[0], oacc[1], oacc[2], oacc[3]};
            f32x4 v1 = {oacc[4], oacc[5], oacc[6], oacc[7]};
            __builtin_nontemporal_store(v0, (f32x4*)op);
            __builtin_nontemporal_store(v1, (f32x4*)(op + 4));
        }
    }
}

extern "C" void kernel_launch(void* const* d_in, const int* in_sizes, int n_in,
                              void* d_out, int out_size, void* d_ws, size_t ws_size,
                              hipStream_t stream) {
    const float* mesh = (const float*)d_in[0];
    const float* bw   = (const float*)d_in[1];
    const float* ic   = (const float*)d_in[2];
    const float* W    = (const float*)d_in[3];
    const float* bias = (const float*)d_in[4];
    const int*   bi   = (const int*)d_in[5];
    float* out = (float*)d_out;

    const int n = in_sizes[0] / FEAT;   // N_VERTS
    const int total = n * FEAT;

    // workspace layout: [0,512) cs3, [512, 512 + n*16*2) bf16 mesh
    float* cs3 = (float*)d_ws;
    u16*   mbf = (u16*)((char*)d_ws + 512);

    cs3_kernel<<<1, 128, 0, stream>>>(ic, cs3);

    const int cvt_threads = (total + 7) / 8;
    cvt_kernel<<<(cvt_threads + BLOCK - 1) / BLOCK, BLOCK, 0, stream>>>(mesh, mbf, total);

    const int blocks = (n + VPB - 1) / VPB;
    conv_kernel<<<blocks, BLOCK, 0, stream>>>(mbf, bw, W, bias, bi, cs3, out, n);
}

// Round 4
// 130.956 us; speedup vs baseline: 1.4868x; 1.0561x over previous
//
#include <hip/hip_runtime.h>

#define KK 40        // N_RADIAL * N_ANGULAR
#define M3 120       // KK * 3
#define MM4 30       // M3 / 4 (float4 chunks of bw/bi)
#define FEAT 16
#define NT 8
#define ODIM 32
#define VPB 64       // vertices per block
#define BLOCK 512

typedef unsigned int u32;
typedef unsigned short u16;
typedef float  f32x4 __attribute__((ext_vector_type(4)));
typedef int    i32x4 __attribute__((ext_vector_type(4)));
typedef u32    u32x4 __attribute__((ext_vector_type(4)));

// cs3[m] = csum[m/3], csum[k] = sum_{ra} ic[ra][k]
__global__ void cs3_kernel(const float* __restrict__ ic, float* __restrict__ cs3) {
    __shared__ float cs[KK];
    const int t = threadIdx.x;
    if (t < KK) {
        float s = 0.f;
        #pragma unroll
        for (int ra = 0; ra < KK; ++ra) s += ic[ra * KK + t];
        cs[t] = s;
    }
    __syncthreads();
    if (t < M3) cs3[t] = cs[t / 3];
}

__device__ __forceinline__ u16 f2bf_rne(float x) {
    u32 u = __float_as_uint(x);
    u32 r = (u + 0x7fffu + ((u >> 16) & 1u)) >> 16;   // round-to-nearest-even
    return (u16)r;
}

// mesh fp32 -> bf16, 8 elements per thread, non-temporal both ways
__global__ void cvt_kernel(const float* __restrict__ mesh, u16* __restrict__ mbf, int total) {
    const int i = blockIdx.x * blockDim.x + threadIdx.x;
    const int base = i * 8;
    if (base < total) {
        f32x4 a = __builtin_nontemporal_load((const f32x4*)(mesh + base));
        f32x4 b = __builtin_nontemporal_load((const f32x4*)(mesh + base + 4));
        u32x4 v;
        v.x = (u32)f2bf_rne(a.x) | ((u32)f2bf_rne(a.y) << 16);
        v.y = (u32)f2bf_rne(a.z) | ((u32)f2bf_rne(a.w) << 16);
        v.z = (u32)f2bf_rne(b.x) | ((u32)f2bf_rne(b.y) << 16);
        v.w = (u32)f2bf_rne(b.z) | ((u32)f2bf_rne(b.w) << 16);
        __builtin_nontemporal_store(v, (u32x4*)(mbf + base));
    }
}

__global__ __launch_bounds__(BLOCK, 4) void conv_kernel(
    const u16*   __restrict__ mbf,    // [N,16] bf16, L2-resident (3.2 MB)
    const float* __restrict__ bw,     // [N,120]
    const float* __restrict__ W,      // [8,32,16]
    const float* __restrict__ bias,   // [8,32]
    const int*   __restrict__ bi,     // [N,120]
    const float* __restrict__ cs3,    // [120]
    float*       __restrict__ out,    // [N,32]
    int n)
{
    __shared__ float s_sig[VPB][FEAT + 1];   // stride 17: conflict-free
    __shared__ float s_out[VPB][ODIM + 1];   // stride 33: conflict-free b32
    __shared__ f32x4 s_cs34[MM4];

    const int tid = threadIdx.x;
    if (tid < MM4) s_cs34[tid] = ((const f32x4*)cs3)[tid];
    __syncthreads();

    // ---------------- Phase 1: gather + interp ----------------
    // 8 lanes per vertex: tid = vloc*8 + jc*4 + mc*2 + q
    //   jc in {0,1}: j-pair {0,1} vs {2,3}
    //   mc in {0,1}: chunk parity (mm = mc, mc+2, ..., mc+28)
    //   q  in {0,1}: feature half (8 bf16 = one 16B gather)
    {
        const int vloc = tid >> 3;
        const int jc   = (tid >> 2) & 1;
        const int mc   = (tid >> 1) & 1;
        const int q    = tid & 1;
        const int vg   = blockIdx.x * VPB + vloc;

        float acc[8];
        #pragma unroll
        for (int e = 0; e < 8; ++e) acc[e] = 0.f;

        if (vg < n) {
            const f32x4* bw4 = (const f32x4*)(bw + (size_t)vg * M3);
            const i32x4* bi4 = (const i32x4*)(bi + (size_t)vg * M3);

            // depth-1 software pipeline on the stream loads
            f32x4 wv = __builtin_nontemporal_load(bw4 + mc);
            i32x4 iv = __builtin_nontemporal_load(bi4 + mc);

            #pragma unroll
            for (int i = 0; i < 15; ++i) {
                const int mm = mc + 2 * i;
                const f32x4 c4 = s_cs34[mm];
                const f32x4 wc = wv;
                const i32x4 ic_ = iv;
                if (i < 14) {
                    wv = __builtin_nontemporal_load(bw4 + mm + 2);
                    iv = __builtin_nontemporal_load(bi4 + mm + 2);
                }
                const float w0 = jc ? (c4.z * wc.z) : (c4.x * wc.x);
                const float w1 = jc ? (c4.w * wc.w) : (c4.y * wc.y);
                const int   i0 = jc ? ic_.z : ic_.x;
                const int   i1 = jc ? ic_.w : ic_.y;

                const u32x4 g0 = *((const u32x4*)(mbf + (size_t)i0 * FEAT) + q);
                const u32x4 g1 = *((const u32x4*)(mbf + (size_t)i1 * FEAT) + q);

                acc[0] = fmaf(w0, __uint_as_float(g0.x << 16),          acc[0]);
                acc[1] = fmaf(w0, __uint_as_float(g0.x & 0xffff0000u), acc[1]);
                acc[2] = fmaf(w0, __uint_as_float(g0.y << 16),          acc[2]);
                acc[3] = fmaf(w0, __uint_as_float(g0.y & 0xffff0000u), acc[3]);
                acc[4] = fmaf(w0, __uint_as_float(g0.z << 16),          acc[4]);
                acc[5] = fmaf(w0, __uint_as_float(g0.z & 0xffff0000u), acc[5]);
                acc[6] = fmaf(w0, __uint_as_float(g0.w << 16),          acc[6]);
                acc[7] = fmaf(w0, __uint_as_float(g0.w & 0xffff0000u), acc[7]);

                acc[0] = fmaf(w1, __uint_as_float(g1.x << 16),          acc[0]);
                acc[1] = fmaf(w1, __uint_as_float(g1.x & 0xffff0000u), acc[1]);
                acc[2] = fmaf(w1, __uint_as_float(g1.y << 16),          acc[2]);
                acc[3] = fmaf(w1, __uint_as_float(g1.y & 0xffff0000u), acc[3]);
                acc[4] = fmaf(w1, __uint_as_float(g1.z << 16),          acc[4]);
                acc[5] = fmaf(w1, __uint_as_float(g1.z & 0xffff0000u), acc[5]);
                acc[6] = fmaf(w1, __uint_as_float(g1.w << 16),          acc[6]);
                acc[7] = fmaf(w1, __uint_as_float(g1.w & 0xffff0000u), acc[7]);
            }
        }

        // reduce across jc (xor 4) then mc (xor 2) — both within the wave
        #pragma unroll
        for (int e = 0; e < 8; ++e) acc[e] += __shfl_xor(acc[e], 4);
        #pragma unroll
        for (int e = 0; e < 8; ++e) acc[e] += __shfl_xor(acc[e], 2);

        if (jc == 0) {
            const f32x4 v = (mc == 0) ? (f32x4){acc[0], acc[1], acc[2], acc[3]}
                                      : (f32x4){acc[4], acc[5], acc[6], acc[7]};
            *(f32x4*)(&s_sig[vloc][q * 8 + mc * 4]) = v;
        }
    }
    __syncthreads();

    // ---------------- Phase 2: fold (W @ s, relu, sum over t) ----------------
    // lane = vertex; wave w (0..7) owns outputs o in [4w, 4w+4).
    {
        const int lane = tid & 63;
        const int wave = __builtin_amdgcn_readfirstlane(tid >> 6);  // 0..7, SGPR

        float s[FEAT];
        #pragma unroll
        for (int f = 0; f < FEAT; ++f) s[f] = s_sig[lane][f];

        float oacc[4];
        #pragma unroll
        for (int oi = 0; oi < 4; ++oi) oacc[oi] = 0.f;

        #pragma unroll 2
        for (int t = 0; t < NT; ++t) {
            #pragma unroll
            for (int oi = 0; oi < 4; ++oi) {
                const int o = wave * 4 + oi;
                float pre = bias[t * ODIM + o];                        // scalar load
                const float* wrow = W + ((size_t)t * ODIM + o) * FEAT; // scalar loads
                #pragma unroll
                for (int f = 0; f < FEAT; ++f)
                    pre = fmaf(wrow[f], s[f], pre);
                oacc[oi] += fmaxf(pre, 0.f);
            }
        }

        #pragma unroll
        for (int oi = 0; oi < 4; ++oi)
            s_out[lane][wave * 4 + oi] = oacc[oi];
    }
    __syncthreads();

    // ---------------- Phase 3: coalesced output write ----------------
    // 8 threads per vertex: thread writes one float4; 8 threads cover the
    // vertex's full 128B line.
    {
        const int v  = tid >> 3;
        const int oq = tid & 7;
        const int vg = blockIdx.x * VPB + v;
        if (vg < n) {
            const f32x4 val = { s_out[v][oq * 4 + 0], s_out[v][oq * 4 + 1],
                                s_out[v][oq * 4 + 2], s_out[v][oq * 4 + 3] };
            __builtin_nontemporal_store(val, (f32x4*)(out + (size_t)vg * ODIM + oq * 4));
        }
    }
}

extern "C" void kernel_launch(void* const* d_in, const int* in_sizes, int n_in,
                              void* d_out, int out_size, void* d_ws, size_t ws_size,
                              hipStream_t stream) {
    const float* mesh = (const float*)d_in[0];
    const float* bw   = (const float*)d_in[1];
    const float* ic   = (const float*)d_in[2];
    const float* W    = (const float*)d_in[3];
    const float* bias = (const float*)d_in[4];
    const int*   bi   = (const int*)d_in[5];
    float* out = (float*)d_out;

    const int n = in_sizes[0] / FEAT;   // N_VERTS
    const int total = n * FEAT;

    // workspace layout: [0,512) cs3, [512, 512 + n*16*2) bf16 mesh
    float* cs3 = (float*)d_ws;
    u16*   mbf = (u16*)((char*)d_ws + 512);

    cs3_kernel<<<1, 128, 0, stream>>>(ic, cs3);

    const int cvt_threads = (total + 7) / 8;
    cvt_kernel<<<(cvt_threads + 255) / 256, 256, 0, stream>>>(mesh, mbf, total);

    const int blocks = (n + VPB - 1) / VPB;
    conv_kernel<<<blocks, BLOCK, 0, stream>>>(mbf, bw, W, bias, bi, cs3, out, n);
}

// Round 5
// 104.286 us; speedup vs baseline: 1.8670x; 1.2557x over previous
//
#include <hip/hip_runtime.h>

#define KK 40        // N_RADIAL * N_ANGULAR
#define M3 120       // KK * 3
#define MM4 30       // float4 chunks of bw/bi per vertex
#define RCH 15       // chunks per staging round
#define FEAT 16
#define NT 8
#define ODIM 32
#define VPB 32       // vertices per block
#define BLOCK 256
#define SST 17       // staged stream row stride (float4 units) — bank-spread

typedef unsigned int u32;
typedef unsigned short u16;
typedef float  f32x4 __attribute__((ext_vector_type(4)));
typedef int    i32x4 __attribute__((ext_vector_type(4)));
typedef u32    u32x4 __attribute__((ext_vector_type(4)));

// cs3[m] = csum[m/3], csum[k] = sum_{ra} ic[ra][k]
__global__ void cs3_kernel(const float* __restrict__ ic, float* __restrict__ cs3) {
    __shared__ float cs[KK];
    const int t = threadIdx.x;
    if (t < KK) {
        float s = 0.f;
        #pragma unroll
        for (int ra = 0; ra < KK; ++ra) s += ic[ra * KK + t];
        cs[t] = s;
    }
    __syncthreads();
    if (t < M3) cs3[t] = cs[t / 3];
}

__device__ __forceinline__ u16 f2bf_rne(float x) {
    u32 u = __float_as_uint(x);
    u32 r = (u + 0x7fffu + ((u >> 16) & 1u)) >> 16;   // round-to-nearest-even
    return (u16)r;
}

// mesh fp32 -> bf16, 8 elements per thread, non-temporal both ways
__global__ void cvt_kernel(const float* __restrict__ mesh, u16* __restrict__ mbf, int total) {
    const int i = blockIdx.x * blockDim.x + threadIdx.x;
    const int base = i * 8;
    if (base < total) {
        f32x4 a = __builtin_nontemporal_load((const f32x4*)(mesh + base));
        f32x4 b = __builtin_nontemporal_load((const f32x4*)(mesh + base + 4));
        u32x4 v;
        v.x = (u32)f2bf_rne(a.x) | ((u32)f2bf_rne(a.y) << 16);
        v.y = (u32)f2bf_rne(a.z) | ((u32)f2bf_rne(a.w) << 16);
        v.z = (u32)f2bf_rne(b.x) | ((u32)f2bf_rne(b.y) << 16);
        v.w = (u32)f2bf_rne(b.z) | ((u32)f2bf_rne(b.w) << 16);
        __builtin_nontemporal_store(v, (u32x4*)(mbf + base));
    }
}

__global__ __launch_bounds__(BLOCK, 8) void conv_kernel(
    const u16*   __restrict__ mbf,    // [N,16] bf16, L2-resident (3.2 MB)
    const float* __restrict__ bw,     // [N,120]
    const float* __restrict__ W,      // [8,32,16]
    const float* __restrict__ bias,   // [8,32]
    const int*   __restrict__ bi,     // [N,120]
    const float* __restrict__ cs3,    // [120]
    float*       __restrict__ out,    // [N,32]
    int n)
{
    // stream staging buffer (bw | bi), reused as s_out in phase 2/3
    __shared__ f32x4 s_buf[VPB * SST * 2];               // 17408 B
    __shared__ float s_sig[VPB][FEAT + 1];               //  2176 B

    f32x4* s_bw4 = s_buf;
    i32x4* s_bi4 = (i32x4*)(s_buf + VPB * SST);
    float (*s_out)[ODIM + 1] = (float(*)[ODIM + 1])s_buf;

    const int tid = threadIdx.x;
    const int vg0 = blockIdx.x * VPB;

    const f32x4* bw4g  = (const f32x4*)bw;
    const i32x4* bi4g  = (const i32x4*)bi;
    const f32x4* cs34g = (const f32x4*)cs3;

    // phase-1 lane mapping: tid = vloc*8 + jc*4 + mc*2 + q
    const int vloc = tid >> 3;
    const int jc   = (tid >> 2) & 1;
    const int mc   = (tid >> 1) & 1;
    const int q    = tid & 1;
    const int vg   = vg0 + vloc;

    float acc[8];
    #pragma unroll
    for (int e = 0; e < 8; ++e) acc[e] = 0.f;

    #pragma unroll
    for (int r = 0; r < 2; ++r) {
        if (r) __syncthreads();   // round-0 LDS reads done before restaging

        // ---- cooperative staging: each stream byte loaded exactly once ----
        // i in [0, VPB*RCH): v = i/15, c = i%15; weights pre-scaled by cs3.
        #pragma unroll
        for (int ii = 0; ii < 2; ++ii) {
            const int i = tid + ii * BLOCK;
            if (i < VPB * RCH) {
                const int v = i / RCH;
                const int c = i - v * RCH;
                if (vg0 + v < n) {
                    const int gchunk = (vg0 + v) * MM4 + r * RCH + c;
                    f32x4 wv = __builtin_nontemporal_load(bw4g + gchunk);
                    i32x4 iv = __builtin_nontemporal_load(bi4g + gchunk);
                    const f32x4 cc = cs34g[r * RCH + c];
                    wv.x *= cc.x; wv.y *= cc.y; wv.z *= cc.z; wv.w *= cc.w;
                    s_bw4[v * SST + c] = wv;
                    s_bi4[v * SST + c] = iv;
                }
            }
        }
        __syncthreads();

        // ---- gather round r: lane handles chunks c = mc, mc+2, ... (<15) ----
        if (vg < n) {
            #pragma unroll
            for (int i = 0; i < 8; ++i) {
                const int c = mc + 2 * i;
                if (c < RCH) {
                    const f32x4 wc = s_bw4[vloc * SST + c];
                    const i32x4 iv = s_bi4[vloc * SST + c];
                    const float w0 = jc ? wc.z : wc.x;
                    const float w1 = jc ? wc.w : wc.y;
                    const int   i0 = jc ? iv.z : iv.x;
                    const int   i1 = jc ? iv.w : iv.y;

                    const u32x4 g0 = *((const u32x4*)(mbf + (size_t)i0 * FEAT) + q);
                    const u32x4 g1 = *((const u32x4*)(mbf + (size_t)i1 * FEAT) + q);

                    acc[0] = fmaf(w0, __uint_as_float(g0.x << 16),          acc[0]);
                    acc[1] = fmaf(w0, __uint_as_float(g0.x & 0xffff0000u), acc[1]);
                    acc[2] = fmaf(w0, __uint_as_float(g0.y << 16),          acc[2]);
                    acc[3] = fmaf(w0, __uint_as_float(g0.y & 0xffff0000u), acc[3]);
                    acc[4] = fmaf(w0, __uint_as_float(g0.z << 16),          acc[4]);
                    acc[5] = fmaf(w0, __uint_as_float(g0.z & 0xffff0000u), acc[5]);
                    acc[6] = fmaf(w0, __uint_as_float(g0.w << 16),          acc[6]);
                    acc[7] = fmaf(w0, __uint_as_float(g0.w & 0xffff0000u), acc[7]);

                    acc[0] = fmaf(w1, __uint_as_float(g1.x << 16),          acc[0]);
                    acc[1] = fmaf(w1, __uint_as_float(g1.x & 0xffff0000u), acc[1]);
                    acc[2] = fmaf(w1, __uint_as_float(g1.y << 16),          acc[2]);
                    acc[3] = fmaf(w1, __uint_as_float(g1.y & 0xffff0000u), acc[3]);
                    acc[4] = fmaf(w1, __uint_as_float(g1.z << 16),          acc[4]);
                    acc[5] = fmaf(w1, __uint_as_float(g1.z & 0xffff0000u), acc[5]);
                    acc[6] = fmaf(w1, __uint_as_float(g1.w << 16),          acc[6]);
                    acc[7] = fmaf(w1, __uint_as_float(g1.w & 0xffff0000u), acc[7]);
                }
            }
        }
    }

    // ---- cross-lane reduce: jc (xor 4) then mc (xor 2) ----
    #pragma unroll
    for (int e = 0; e < 8; ++e) acc[e] += __shfl_xor(acc[e], 4);
    #pragma unroll
    for (int e = 0; e < 8; ++e) acc[e] += __shfl_xor(acc[e], 2);

    if (jc == 0) {
        const f32x4 v = (mc == 0) ? (f32x4){acc[0], acc[1], acc[2], acc[3]}
                                  : (f32x4){acc[4], acc[5], acc[6], acc[7]};
        *(f32x4*)(&s_sig[vloc][q * 8 + mc * 4]) = v;
    }
    __syncthreads();   // s_sig ready; stream reads all done (s_buf reusable)

    // ---------------- Phase 2: fold (W @ s, relu, sum over t) ----------------
    // wave w owns outputs [8w, 8w+8); lanes 0-31 and 32-63 mirror (32 verts).
    {
        const int lane = tid & 63;
        const int wave = __builtin_amdgcn_readfirstlane(tid >> 6);  // 0..3
        const int v    = lane & (VPB - 1);

        float s[FEAT];
        #pragma unroll
        for (int f = 0; f < FEAT; ++f) s[f] = s_sig[v][f];

        float oacc[8];
        #pragma unroll
        for (int oi = 0; oi < 8; ++oi) oacc[oi] = 0.f;

        #pragma unroll 2
        for (int t = 0; t < NT; ++t) {
            #pragma unroll
            for (int oi = 0; oi < 8; ++oi) {
                const int o = wave * 8 + oi;
                float pre = bias[t * ODIM + o];                        // scalar load
                const float* wrow = W + ((size_t)t * ODIM + o) * FEAT; // scalar loads
                #pragma unroll
                for (int f = 0; f < FEAT; ++f)
                    pre = fmaf(wrow[f], s[f], pre);
                oacc[oi] += fmaxf(pre, 0.f);
            }
        }

        if (lane < VPB) {
            #pragma unroll
            for (int oi = 0; oi < 8; ++oi)
                s_out[v][wave * 8 + oi] = oacc[oi];
        }
    }
    __syncthreads();

    // ---------------- Phase 3: coalesced output write ----------------
    // 8 threads per vertex; each writes one float4 -> full 128B line/vertex.
    {
        const int v  = tid >> 3;
        const int oq = tid & 7;
        const int vgo = vg0 + v;
        if (vgo < n) {
            const f32x4 val = { s_out[v][oq * 4 + 0], s_out[v][oq * 4 + 1],
                                s_out[v][oq * 4 + 2], s_out[v][oq * 4 + 3] };
            __builtin_nontemporal_store(val, (f32x4*)(out + (size_t)vgo * ODIM + oq * 4));
        }
    }
}

extern "C" void kernel_launch(void* const* d_in, const int* in_sizes, int n_in,
                              void* d_out, int out_size, void* d_ws, size_t ws_size,
                              hipStream_t stream) {
    const float* mesh = (const float*)d_in[0];
    const float* bw   = (const float*)d_in[1];
    const float* ic   = (const float*)d_in[2];
    const float* W    = (const float*)d_in[3];
    const float* bias = (const float*)d_in[4];
    const int*   bi   = (const int*)d_in[5];
    float* out = (float*)d_out;

    const int n = in_sizes[0] / FEAT;   // N_VERTS
    const int total = n * FEAT;

    // workspace layout: [0,512) cs3, [512, 512 + n*16*2) bf16 mesh
    float* cs3 = (float*)d_ws;
    u16*   mbf = (u16*)((char*)d_ws + 512);

    cs3_kernel<<<1, 128, 0, stream>>>(ic, cs3);

    const int cvt_threads = (total + 7) / 8;
    cvt_kernel<<<(cvt_threads + 255) / 256, 256, 0, stream>>>(mesh, mbf, total);

    const int blocks = (n + VPB - 1) / VPB;
    conv_kernel<<<blocks, BLOCK, 0, stream>>>(mbf, bw, W, bias, bi, cs3, out, n);
}